// Round 13
// baseline (227.120 us; speedup 1.0000x reference)
//
#include <hip/hip_runtime.h>
#include <hip/hip_bf16.h>
#include <math.h>

#define B_    2
#define Q_    1024
#define H_    32
#define KVH_  8
#define HD_   64
#define HS_   2048
#define NREP_ 4
#define KIN_  (2*HS_)            // 4096
#define M_    (B_*Q_)            // 2048
#define QKVN_ (H_*HD_ + 2*KVH_*HD_)  // 3072
#define AOW_  (H_*HD_)           // 2048
#define SCALE_ 0.125f            // 1/sqrt(64)

typedef __attribute__((ext_vector_type(8))) short bf16x8;
typedef __attribute__((ext_vector_type(4))) float f32x4;
typedef unsigned short u16;

static __device__ __forceinline__ u16 f2b(float f) {
  union { float f; unsigned int u; } c; c.f = f;
  unsigned int r = (c.u + 0x7fffu + ((c.u >> 16) & 1u)) >> 16;
  return (u16)r;
}
static __device__ __forceinline__ float b2f(u16 s) {
  union { unsigned int u; float f; } c;
  c.u = ((unsigned int)s) << 16;
  return c.f;
}
static __device__ __forceinline__ unsigned long long pack4s(float4 v, float sc) {
  return (unsigned long long)f2b(v.x*sc) |
         ((unsigned long long)f2b(v.y*sc) << 16) |
         ((unsigned long long)f2b(v.z*sc) << 32) |
         ((unsigned long long)f2b(v.w*sc) << 48);
}

#define GLOAD(SRC, DST) __builtin_amdgcn_global_load_lds( \
    (const __attribute__((address_space(1))) void*)(SRC), \
    (__attribute__((address_space(3))) void*)(DST), 16, 0, 0)

// ---------------- merged prep: K/V transpose-cast (blocks 0..1023) + flat casts ----------------
__global__ __launch_bounds__(256) void prep_kernel(
    const float* __restrict__ hidden, const float* __restrict__ Wq,
    const float* __restrict__ Wk, const float* __restrict__ Wv,
    const float* __restrict__ Wo,
    const float* __restrict__ k0, const float* __restrict__ v0,
    u16* __restrict__ Xb, u16* __restrict__ Wb, u16* __restrict__ Wob,
    u16* __restrict__ Kb, u16* __restrict__ Vtb)
{
  __shared__ float Vs[64][65];
  const int bx = blockIdx.x;
  const int t = threadIdx.x;
  if (bx < 1024) {
    // ---- cache K/V -> bf16 attn-ready swizzled layouts ----
    const int kt = bx & 15, bh = bx >> 4;
    const int r = t >> 2, seg = t & 3;
    {
      const float* sp = k0 + ((size_t)bh*Q_ + (kt<<6) + r)*64;
      u16* dp = Kb + ((size_t)bh*Q_ + (kt<<6) + r)*64;
#pragma unroll
      for (int c2 = 2*seg; c2 < 2*seg+2; ++c2) {
        int ca = c2 ^ (r & 7);
        float4 a = *(const float4*)(sp + ca*8);
        float4 b = *(const float4*)(sp + ca*8 + 4);
        unsigned long long o[2] = {pack4s(a,1.f), pack4s(b,1.f)};
        *(float4*)(dp + c2*8) = *(const float4*)o;
      }
    }
    {
      const float* sp = v0 + ((size_t)bh*Q_ + (kt<<6) + r)*64 + seg*16;
#pragma unroll
      for (int c = 0; c < 4; ++c) {
        float4 v = *(const float4*)(sp + 4*c);
        Vs[r][seg*16 + 4*c + 0] = v.x; Vs[r][seg*16 + 4*c + 1] = v.y;
        Vs[r][seg*16 + 4*c + 2] = v.z; Vs[r][seg*16 + 4*c + 3] = v.w;
      }
    }
    __syncthreads();
    {
      const int d = r;
      u16* dp = Vtb + ((size_t)bh*64 + d)*Q_ + (kt<<6);
#pragma unroll
      for (int c2 = 2*seg; c2 < 2*seg+2; ++c2) {
        int ca = c2 ^ (d & 7);
        u16 o[8];
#pragma unroll
        for (int j = 0; j < 8; ++j) o[j] = f2b(Vs[ca*8 + j][d]);
        *(float4*)(dp + c2*8) = *(const float4*)o;
      }
    }
  } else {
    // ---- flat fp32 -> bf16 casts, grid-strided over 2048 blocks ----
    const int U0 = 1048576;            // hidden (2048*4096/8)
    const int U1 = U0 + 1048576;       // +Wq
    const int U2 = U1 + 262144;        // +Wk    (512*4096/8)
    const int U3 = U2 + 262144;        // +Wv
    const int U4 = U3 + 524288;        // +Wo    (2048*2048/8)
    for (int u = (bx - 1024)*256 + t; u < U4; u += 2048*256) {
      const float* src; u16* dst;
      if (u < U0)      { src = hidden + (size_t)u*8;   dst = Xb + (size_t)u*8; }
      else if (u < U1) { src = Wq + (size_t)(u-U0)*8;  dst = Wb + (size_t)(u-U0)*8; }
      else if (u < U2) { src = Wk + (size_t)(u-U1)*8;  dst = Wb + (size_t)2048*KIN_ + (size_t)(u-U1)*8; }
      else if (u < U3) { src = Wv + (size_t)(u-U2)*8;  dst = Wb + (size_t)2560*KIN_ + (size_t)(u-U2)*8; }
      else             { src = Wo + (size_t)(u-U3)*8;  dst = Wob + (size_t)(u-U3)*8; }
      float4 a = *(const float4*)src;
      float4 bb = *(const float4*)(src + 4);
      unsigned long long o[2] = {pack4s(a, 1.f), pack4s(bb, 1.f)};
      *(float4*)dst = *(const float4*)o;
    }
  }
}

// ---------------- bf16 NT MFMA GEMM, 128x64, BK=64 ----------------
// A: LDS-staged double-buffer (global_load_lds, swizzled).  B: DIRECT global->register
// with one-K-step prefetch (cuts LDS fragment reads 12->8 and staging gloads 6->4 per
// wave-step; LDS 48->32 KB -> 4 blocks/CU).  In-thread RoPE epilogue (QKV mode):
// B-fragment columns {wc*16+sub, 32+wc*16+sub} put the RoPE pair (d,d+32) in one
// thread's acc[mi][0]/acc[mi][1].
template<bool QKV>
__global__ __launch_bounds__(256, 4) void gemm_nt(
    const u16* __restrict__ A, const u16* __restrict__ W,
    void* __restrict__ Cv, int K, int ldc, const int* __restrict__ pos_ids)
{
  __shared__ u16 As[2*128*64];   // 32 KB (A dbuf only)
  const int m0 = blockIdx.y << 7, n0 = blockIdx.x << 6;
  const int t = threadIdx.x;
  const int wave = t >> 6, lane = t & 63;
  const int wr = wave >> 1, wc = wave & 1;

  f32x4 acc[4][2] = {};

  const int lrow8 = lane >> 3;
  const int lcsw  = ((lane & 7) ^ lrow8) * 8;
  const int fr    = lane & 15;
  const int g     = lane >> 4;
  const int sub   = lane & 15;

  const u16* Brow = W + (size_t)(n0 + wc*16 + fr) * K;   // ni adds 32 rows

#define STAGE_A(BUF, K0) do { \
    _Pragma("unroll") \
    for (int p = 0; p < 4; ++p) { \
      int rbase = p * 32 + wave * 8; \
      GLOAD(A + (size_t)(m0 + rbase + lrow8) * K + (K0) + lcsw, \
            As + (BUF)*8192 + rbase * 64); \
    } \
  } while(0)
#define LOAD_B(DST, K0) do { \
    _Pragma("unroll") \
    for (int ni = 0; ni < 2; ++ni) \
      _Pragma("unroll") \
      for (int kk = 0; kk < 2; ++kk) \
        DST[ni][kk] = *(const bf16x8*)(Brow + (size_t)ni*32*K + (K0) + (kk*4+g)*8); \
  } while(0)

  bf16x8 bcur[2][2], bnxt[2][2];
  STAGE_A(0, 0);
  LOAD_B(bcur, 0);
  int cur = 0;
  for (int k0 = 0; k0 < K; k0 += 64) {
    if (k0 + 64 < K) {
      STAGE_A(cur ^ 1, k0 + 64);
      LOAD_B(bnxt, k0 + 64);
      asm volatile("s_waitcnt vmcnt(8)" ::: "memory");   // drain prev iter's A-stage + B
    } else {
      asm volatile("s_waitcnt vmcnt(0)" ::: "memory");
    }
    asm volatile("s_barrier" ::: "memory");

    const u16* Ab = As + cur*8192;
    bf16x8 af[4][2];
#pragma unroll
    for (int kk = 0; kk < 2; ++kk) {
      int ck = kk * 4 + g;
#pragma unroll
      for (int mi = 0; mi < 4; ++mi) {
        int row = wr * 64 + mi * 16 + fr;
        af[mi][kk] = *(const bf16x8*)(Ab + row * 64 + ((ck ^ (row & 7)) << 3));
      }
    }
    __builtin_amdgcn_s_setprio(1);
#pragma unroll
    for (int kk = 0; kk < 2; ++kk)
#pragma unroll
      for (int mi = 0; mi < 4; ++mi)
#pragma unroll
        for (int ni = 0; ni < 2; ++ni)
          acc[mi][ni] = __builtin_amdgcn_mfma_f32_16x16x32_bf16(af[mi][kk], bcur[ni][kk], acc[mi][ni], 0, 0, 0);
    __builtin_amdgcn_s_setprio(0);
    asm volatile("s_barrier" ::: "memory");
#pragma unroll
    for (int ni = 0; ni < 2; ++ni)
#pragma unroll
      for (int kk = 0; kk < 2; ++kk)
        bcur[ni][kk] = bnxt[ni][kk];
    cur ^= 1;
  }
#undef STAGE_A
#undef LOAD_B

  if (QKV && n0 < 2560) {
    // ---- in-thread RoPE epilogue: pair = (acc[mi][0], acc[mi][1]) ----
    u16* outp = (u16*)Cv;
    const bool isq = (n0 < 2048);
    const float qs = isq ? SCALE_ : 1.0f;
    const int d = wc*16 + sub;                  // freq index 0..31
    const float inv = exp2f(-0.4152410118609203f * (float)d);
#pragma unroll
    for (int mi = 0; mi < 4; ++mi) {
#pragma unroll
      for (int r = 0; r < 4; ++r) {
        int m = m0 + wr*64 + mi*16 + g*4 + r;
        float p = (float)(pos_ids[m] + 2);
        float f = p * inv, s, c;
        __sincosf(f, &s, &c);
        float x0 = acc[mi][0][r], x1 = acc[mi][1][r];
        outp[(size_t)m * ldc + n0 + d]      = f2b((x0*c - x1*s) * qs);
        outp[(size_t)m * ldc + n0 + 32 + d] = f2b((x1*c + x0*s) * qs);
      }
    }
  } else {
#pragma unroll
    for (int mi = 0; mi < 4; ++mi) {
      int rbase = m0 + wr * 64 + mi * 16 + g * 4;
#pragma unroll
      for (int ni = 0; ni < 2; ++ni) {
        int col = n0 + wc*16 + ni*32 + sub;
#pragma unroll
        for (int r = 0; r < 4; ++r) {
          if (QKV) ((u16*)Cv)[(size_t)(rbase + r) * ldc + col] = f2b(acc[mi][ni][r]);
          else     ((float*)Cv)[(size_t)(rbase + r) * ldc + col] = acc[mi][ni][r];
        }
      }
    }
  }
}

// ---------------- MFMA flash attention: QBLK=128, 8 waves, DMA K/V, dbuf ----------------
__global__ __launch_bounds__(512, 4) void attn_mfma(
    const u16* __restrict__ Yb,         // [M_][3072] bf16, rope applied, q scaled
    const u16* __restrict__ Kb,         // [bh][Q][64] swizzled bf16
    const u16* __restrict__ Vtb,        // [bh][64][Q] swizzled bf16
    const float* __restrict__ cache_k,  // [2][B][H][Q][64] fp32
    const float* __restrict__ cache_v,
    u16* __restrict__ AOb)              // [M_][2048] bf16
{
  __shared__ u16 Qs[128*64];
  __shared__ u16 Ps[128*64];
  __shared__ u16 Ks[2*64*64];
  __shared__ u16 Vt[2*64*64];

  const int bid = blockIdx.x;
  const int xcd = bid & 7, within = bid >> 3;
  const int w8 = within & 7;
  const int qtb = (w8 & 1) ? (7 - (w8 >> 1)) : (w8 >> 1);
  const int pair = xcd * 8 + (within >> 3);
  const int h = pair >> 1, b = pair & 1;
  const int bh = b * H_ + h;

  const int t = threadIdx.x;
  const int wave = t >> 6, lane = t & 63;
  const int g = lane >> 4, sub = lane & 15;
  const int wq0 = wave * 16;
  const int srow = lane >> 3;
  const int scc  = lane & 7;

  const u16* KbT = Kb + (size_t)bh * Q_ * 64;
  const u16* VtT = Vtb + (size_t)bh * 64 * Q_;

#define ATTN_STAGE(BUF, KT) do { \
    int r_ = wave*8 + srow; \
    GLOAD(KbT + (size_t)(((KT)<<6) + r_)*64 + scc*8, Ks + (BUF)*4096 + wave*512); \
    GLOAD(VtT + (size_t)r_*Q_ + ((KT)<<6) + scc*8,   Vt + (BUF)*4096 + wave*512); \
  } while(0)

  {
#pragma unroll
    for (int p = 0; p < 2; ++p) {
      int r = p*64 + wave*8 + srow;
      GLOAD(Yb + (size_t)(b*Q_ + qtb*128 + r)*QKVN_ + h*64 + ((scc ^ (r&7))<<3),
            Qs + p*4096 + wave*512);
    }
  }
  ATTN_STAGE(0, 0);
  asm volatile("s_waitcnt vmcnt(2)" ::: "memory");
  asm volatile("s_barrier" ::: "memory");

  bf16x8 qb[2];
#pragma unroll
  for (int kk = 0; kk < 2; ++kk) {
    int row = wq0 + sub;
    qb[kk] = *(const bf16x8*)&Qs[row*64 + (((4*kk+g) ^ (row&7))<<3)];
  }

  float m_run = -3e38f, l_run = 0.f;
  f32x4 acc_o[4] = {};
  int cur = 0;
  const int nkt = 2*qtb + 2;

  for (int kt = 0; kt < nkt; ++kt) {
    if (kt + 1 < nkt) {
      ATTN_STAGE(cur ^ 1, kt + 1);
      asm volatile("s_waitcnt vmcnt(2)" ::: "memory");
    } else {
      asm volatile("s_waitcnt vmcnt(0)" ::: "memory");
    }
    asm volatile("s_barrier" ::: "memory");

    if (kt*64 <= qtb*128 + wq0 + 15) {
      const u16* ksb = Ks + cur*4096;
      const u16* vtb = Vt + cur*4096;

      f32x4 s[4] = {};
      __builtin_amdgcn_s_setprio(1);
#pragma unroll
      for (int kk = 0; kk < 2; ++kk) {
        int kb = 4*kk + g;
#pragma unroll
        for (int cb = 0; cb < 4; ++cb) {
          int krow = cb*16 + sub;
          bf16x8 kf = *(const bf16x8*)&ksb[krow*64 + ((kb ^ (krow&7))<<3)];
          s[cb] = __builtin_amdgcn_mfma_f32_16x16x32_bf16(kf, qb[kk], s[cb], 0, 0, 0);
        }
      }
      __builtin_amdgcn_s_setprio(0);

      if (kt >= 2*qtb) {
#pragma unroll
        for (int cb = 0; cb < 4; ++cb)
#pragma unroll
          for (int r = 0; r < 4; ++r)
            if (kt*64 + cb*16 + 4*g + r > qtb*128 + wq0 + sub) s[cb][r] = -3e38f;
      }

      float mt = -3e38f;
#pragma unroll
      for (int cb = 0; cb < 4; ++cb)
#pragma unroll
        for (int r = 0; r < 4; ++r) mt = fmaxf(mt, s[cb][r]);
      mt = fmaxf(mt, __shfl_xor(mt, 16, 64));
      mt = fmaxf(mt, __shfl_xor(mt, 32, 64));

      float al = 1.0f;
      if (__any(mt > m_run + 8.f)) {
        float mnew = fmaxf(m_run, mt);
        al = __expf(m_run - mnew);
        m_run = mnew;
        int base = (lane & 48) + ((lane & 48) >> 2);
#pragma unroll
        for (int r = 0; r < 4; ++r) {
          float alr = __shfl(al, base + r, 64);
#pragma unroll
          for (int db = 0; db < 4; ++db) acc_o[db][r] *= alr;
        }
      }

      float sum = 0.f;
#pragma unroll
      for (int cb = 0; cb < 4; ++cb) {
        float p0 = __expf(s[cb][0]-m_run), p1 = __expf(s[cb][1]-m_run);
        float p2 = __expf(s[cb][2]-m_run), p3 = __expf(s[cb][3]-m_run);
        sum += (p0+p1)+(p2+p3);
        unsigned long long pk =
            (unsigned long long)((unsigned int)f2b(p0) | ((unsigned int)f2b(p1)<<16)) |
            ((unsigned long long)((unsigned int)f2b(p2) | ((unsigned int)f2b(p3)<<16)) << 32);
        int col8 = cb*2 + (g>>1);
        int dst = (wq0 + sub)*64 + ((col8 ^ (sub&7))<<3) + ((g&1)<<2);
        *(unsigned long long*)&Ps[dst] = pk;
      }
      sum += __shfl_xor(sum, 16, 64);
      sum += __shfl_xor(sum, 32, 64);
      l_run = l_run*al + sum;

      __builtin_amdgcn_s_setprio(1);
#pragma unroll
      for (int kk = 0; kk < 2; ++kk) {
        bf16x8 pa = *(const bf16x8*)&Ps[(wq0 + sub)*64 + (((4*kk+g) ^ (sub&7))<<3)];
#pragma unroll
        for (int db = 0; db < 4; ++db) {
          int drow = db*16 + sub;
          bf16x8 vf = *(const bf16x8*)&vtb[drow*64 + (((4*kk+g) ^ (drow&7))<<3)];
          acc_o[db] = __builtin_amdgcn_mfma_f32_16x16x32_bf16(pa, vf, acc_o[db], 0, 0, 0);
        }
      }
      __builtin_amdgcn_s_setprio(0);
    }
    asm volatile("s_barrier" ::: "memory");
    cur ^= 1;
  }
#undef ATTN_STAGE

  const int qrow_mine = wq0 + sub;
  const int qpos_mine = qtb*128 + qrow_mine;
  float e1 = 0.f, e2 = 0.f;
  {
    const float* k1p = cache_k + ((size_t)((B_ + b)*H_ + h)*Q_ + qpos_mine)*HD_ + g*16;
    const u16*   kfp = Yb + (size_t)(b*Q_ + qpos_mine)*QKVN_ + H_*HD_ + (h/NREP_)*HD_ + g*16;
    float qv[16];
#pragma unroll
    for (int half = 0; half < 2; ++half) {
      int kb = 2*g + half;
      bf16x8 qq = *(const bf16x8*)&Qs[qrow_mine*64 + ((kb ^ (qrow_mine&7))<<3)];
#pragma unroll
      for (int i = 0; i < 8; ++i) qv[half*8 + i] = b2f(((u16)qq[i]));
    }
    float4 kf4a = *(const float4*)kfp;
    float4 kf4b = *(const float4*)(kfp + 8);
    const u16* kf16a = (const u16*)&kf4a;
    const u16* kf16b = (const u16*)&kf4b;
#pragma unroll
    for (int c = 0; c < 4; ++c) {
      float4 kv1 = *(const float4*)(k1p + 4*c);
      e1 += qv[4*c]*kv1.x + qv[4*c+1]*kv1.y + qv[4*c+2]*kv1.z + qv[4*c+3]*kv1.w;
    }
#pragma unroll
    for (int i = 0; i < 8; ++i) {
      e2 += qv[i]   * b2f(kf16a[i]);
      e2 += qv[8+i] * b2f(kf16b[i]);
    }
  }
  e1 += __shfl_xor(e1, 16, 64); e1 += __shfl_xor(e1, 32, 64);
  e2 += __shfl_xor(e2, 16, 64); e2 += __shfl_xor(e2, 32, 64);

#pragma unroll
  for (int r = 0; r < 4; ++r) {
    int row = 4*g + r;
    int src = (lane & 48) | row;
    float e1r = __shfl(e1, src, 64);
    float e2r = __shfl(e2, src, 64);
    float m_r = __shfl(m_run, src, 64);
    float l_r = __shfl(l_run, src, 64);
    float mnew = fmaxf(m_r, fmaxf(e1r, e2r));
    float alr = __expf(m_r - mnew);
    float w1  = __expf(e1r - mnew);
    float w2  = __expf(e2r - mnew);
    float linv = 1.f / (l_r*alr + w1 + w2);
    int qpos = qtb*128 + wq0 + row;
    const float* v1p = cache_v + ((size_t)((B_ + b)*H_ + h)*Q_ + qpos)*HD_;
    const u16*   vfp = Yb + (size_t)(b*Q_ + qpos)*QKVN_ + (H_*HD_ + KVH_*HD_) + (h/NREP_)*HD_;
    u16* op = AOb + (size_t)(b*Q_ + qpos)*AOW_ + h*HD_;
#pragma unroll
    for (int db = 0; db < 4; ++db) {
      int d = db*16 + sub;
      float o = (acc_o[db][r]*alr + w1*v1p[d] + w2*b2f(vfp[d])) * linv;
      op[d] = f2b(o);
    }
  }
}

extern "C" void kernel_launch(void* const* d_in, const int* in_sizes, int n_in,
                              void* d_out, int out_size, void* d_ws, size_t ws_size,
                              hipStream_t stream) {
  const float* hidden  = (const float*)d_in[0];
  const float* Wq      = (const float*)d_in[1];
  const float* Wk      = (const float*)d_in[2];
  const float* Wv      = (const float*)d_in[3];
  const float* Wo      = (const float*)d_in[4];   // [HS][H*HD]
  const float* cache_k = (const float*)d_in[5];
  const float* cache_v = (const float*)d_in[6];
  const int*   pos_ids = (const int*)d_in[8];
  float* out = (float*)d_out;

  char* ws = (char*)d_ws;
  u16* Yb  = (u16*)ws;  ws += (size_t)M_ * QKVN_ * 2;
  u16* Xb  = (u16*)ws;  ws += (size_t)M_ * KIN_ * 2;
  u16* Wb  = (u16*)ws;  ws += (size_t)QKVN_ * KIN_ * 2;
  u16* Wob = (u16*)ws;  ws += (size_t)HS_ * AOW_ * 2;
  u16* Kb  = (u16*)ws;  ws += (size_t)B_*H_*Q_*64 * 2;
  u16* Vtb = (u16*)ws;  ws += (size_t)B_*H_*Q_*64 * 2;
  u16* AOb = Xb;                                           // Xb dead after QKV GEMM

  prep_kernel<<<dim3(3072), 256, 0, stream>>>(
      hidden, Wq, Wk, Wv, Wo, cache_k, cache_v, Xb, Wb, Wob, Kb, Vtb);

  // QKV GEMM with fused in-thread RoPE epilogue: grid 48x16 = 768 blocks
  gemm_nt<true><<<dim3(QKVN_/64, M_/128), 256, 0, stream>>>(Xb, Wb, (void*)Yb, KIN_, QKVN_, pos_ids);
  // attention: 512 blocks x 512 threads
  attn_mfma<<<dim3(512), 512, 0, stream>>>(Yb, Kb, Vtb, cache_k, cache_v, AOb);
  // Wo GEMM: grid 32x16 = 512 blocks, fp32 out
  gemm_nt<false><<<dim3(HS_/64, M_/128), 256, 0, stream>>>(AOb, Wob, (void*)out, AOW_, HS_, nullptr);
}

// Round 14
// 171.062 us; speedup vs baseline: 1.3277x; 1.3277x over previous
//
#include <hip/hip_runtime.h>
#include <hip/hip_bf16.h>
#include <math.h>

#define B_    2
#define Q_    1024
#define H_    32
#define KVH_  8
#define HD_   64
#define HS_   2048
#define NREP_ 4
#define KIN_  (2*HS_)            // 4096
#define M_    (B_*Q_)            // 2048
#define QKVN_ (H_*HD_ + 2*KVH_*HD_)  // 3072
#define AOW_  (H_*HD_)           // 2048
#define SCALE_ 0.125f            // 1/sqrt(64)

typedef __attribute__((ext_vector_type(8))) short bf16x8;
typedef __attribute__((ext_vector_type(4))) float f32x4;
typedef unsigned short u16;

static __device__ __forceinline__ u16 f2b(float f) {
  union { float f; unsigned int u; } c; c.f = f;
  unsigned int r = (c.u + 0x7fffu + ((c.u >> 16) & 1u)) >> 16;
  return (u16)r;
}
static __device__ __forceinline__ float b2f(u16 s) {
  union { unsigned int u; float f; } c;
  c.u = ((unsigned int)s) << 16;
  return c.f;
}
static __device__ __forceinline__ unsigned long long pack4s(float4 v, float sc) {
  return (unsigned long long)f2b(v.x*sc) |
         ((unsigned long long)f2b(v.y*sc) << 16) |
         ((unsigned long long)f2b(v.z*sc) << 32) |
         ((unsigned long long)f2b(v.w*sc) << 48);
}

#define GLOAD(SRC, DST) __builtin_amdgcn_global_load_lds( \
    (const __attribute__((address_space(1))) void*)(SRC), \
    (__attribute__((address_space(3))) void*)(DST), 16, 0, 0)

// ---------------- merged prep: K/V transpose-cast (blocks 0..1023) + flat casts ----------------
__global__ __launch_bounds__(256) void prep_kernel(
    const float* __restrict__ hidden, const float* __restrict__ Wq,
    const float* __restrict__ Wk, const float* __restrict__ Wv,
    const float* __restrict__ Wo,
    const float* __restrict__ k0, const float* __restrict__ v0,
    u16* __restrict__ Xb, u16* __restrict__ Wb, u16* __restrict__ Wob,
    u16* __restrict__ Kb, u16* __restrict__ Vtb)
{
  __shared__ float Vs[64][65];
  const int bx = blockIdx.x;
  const int t = threadIdx.x;
  if (bx < 1024) {
    const int kt = bx & 15, bh = bx >> 4;
    const int r = t >> 2, seg = t & 3;
    {
      const float* sp = k0 + ((size_t)bh*Q_ + (kt<<6) + r)*64;
      u16* dp = Kb + ((size_t)bh*Q_ + (kt<<6) + r)*64;
#pragma unroll
      for (int c2 = 2*seg; c2 < 2*seg+2; ++c2) {
        int ca = c2 ^ (r & 7);
        float4 a = *(const float4*)(sp + ca*8);
        float4 b = *(const float4*)(sp + ca*8 + 4);
        unsigned long long o[2] = {pack4s(a,1.f), pack4s(b,1.f)};
        *(float4*)(dp + c2*8) = *(const float4*)o;
      }
    }
    {
      const float* sp = v0 + ((size_t)bh*Q_ + (kt<<6) + r)*64 + seg*16;
#pragma unroll
      for (int c = 0; c < 4; ++c) {
        float4 v = *(const float4*)(sp + 4*c);
        Vs[r][seg*16 + 4*c + 0] = v.x; Vs[r][seg*16 + 4*c + 1] = v.y;
        Vs[r][seg*16 + 4*c + 2] = v.z; Vs[r][seg*16 + 4*c + 3] = v.w;
      }
    }
    __syncthreads();
    {
      const int d = r;
      u16* dp = Vtb + ((size_t)bh*64 + d)*Q_ + (kt<<6);
#pragma unroll
      for (int c2 = 2*seg; c2 < 2*seg+2; ++c2) {
        int ca = c2 ^ (d & 7);
        u16 o[8];
#pragma unroll
        for (int j = 0; j < 8; ++j) o[j] = f2b(Vs[ca*8 + j][d]);
        *(float4*)(dp + c2*8) = *(const float4*)o;
      }
    }
  } else {
    const int U0 = 1048576;
    const int U1 = U0 + 1048576;
    const int U2 = U1 + 262144;
    const int U3 = U2 + 262144;
    const int U4 = U3 + 524288;
    for (int u = (bx - 1024)*256 + t; u < U4; u += 2048*256) {
      const float* src; u16* dst;
      if (u < U0)      { src = hidden + (size_t)u*8;   dst = Xb + (size_t)u*8; }
      else if (u < U1) { src = Wq + (size_t)(u-U0)*8;  dst = Wb + (size_t)(u-U0)*8; }
      else if (u < U2) { src = Wk + (size_t)(u-U1)*8;  dst = Wb + (size_t)2048*KIN_ + (size_t)(u-U1)*8; }
      else if (u < U3) { src = Wv + (size_t)(u-U2)*8;  dst = Wb + (size_t)2560*KIN_ + (size_t)(u-U2)*8; }
      else             { src = Wo + (size_t)(u-U3)*8;  dst = Wob + (size_t)(u-U3)*8; }
      float4 a = *(const float4*)src;
      float4 bb = *(const float4*)(src + 4);
      unsigned long long o[2] = {pack4s(a, 1.f), pack4s(bb, 1.f)};
      *(float4*)dst = *(const float4*)o;
    }
  }
}

// ---------------- QKV GEMM: 128x128 tile, 4 waves x (64x64), BK=64, dbuf ----------------
// Per wave K-step: 16 b128 LDS reads : 32 MFMAs (1.5x better ratio than 128x64).
// In-thread RoPE: wave's 64 cols = one head; pair (d,d+32) = (acc[mi][ni], acc[mi][ni+2]).
__global__ __launch_bounds__(256, 2) void gemm_qkv(
    const u16* __restrict__ A, const u16* __restrict__ W,
    u16* __restrict__ C, int K, int ldc, const int* __restrict__ pos_ids)
{
  __shared__ u16 As[2*128*64];   // 32 KB
  __shared__ u16 Bs[2*128*64];   // 32 KB
  const int m0 = blockIdx.y << 7, n0 = blockIdx.x << 7;
  const int t = threadIdx.x;
  const int wave = t >> 6, lane = t & 63;
  const int wr = wave >> 1, wc = wave & 1;

  f32x4 acc[4][4] = {};

  const int lrow8 = lane >> 3;
  const int lcsw  = ((lane & 7) ^ lrow8) * 8;
  const int fr    = lane & 15;
  const int g     = lane >> 4;
  const int sub   = lane & 15;

#define STAGE2(BUF, K0) do { \
    _Pragma("unroll") \
    for (int p = 0; p < 4; ++p) { \
      int rbase = p * 32 + wave * 8; \
      GLOAD(A + (size_t)(m0 + rbase + lrow8) * K + (K0) + lcsw, \
            As + (BUF)*8192 + rbase * 64); \
      GLOAD(W + (size_t)(n0 + rbase + lrow8) * K + (K0) + lcsw, \
            Bs + (BUF)*8192 + rbase * 64); \
    } \
  } while(0)

  STAGE2(0, 0);
  int cur = 0;
  for (int k0 = 0; k0 < K; k0 += 64) {
    if (k0 + 64 < K) {
      STAGE2(cur ^ 1, k0 + 64);
      asm volatile("s_waitcnt vmcnt(8)" ::: "memory");   // 8 new in flight; prev done
    } else {
      asm volatile("s_waitcnt vmcnt(0)" ::: "memory");
    }
    asm volatile("s_barrier" ::: "memory");

    const u16* Ab = As + cur*8192;
    const u16* Bb = Bs + cur*8192;
    bf16x8 af[4][2], bfr[4][2];
#pragma unroll
    for (int kk = 0; kk < 2; ++kk) {
      int ck = kk * 4 + g;
#pragma unroll
      for (int mi = 0; mi < 4; ++mi) {
        int row = wr * 64 + mi * 16 + fr;
        af[mi][kk] = *(const bf16x8*)(Ab + row * 64 + ((ck ^ (row & 7)) << 3));
      }
#pragma unroll
      for (int ni = 0; ni < 4; ++ni) {
        int row = wc * 64 + ni * 16 + fr;
        bfr[ni][kk] = *(const bf16x8*)(Bb + row * 64 + ((ck ^ (row & 7)) << 3));
      }
    }
    __builtin_amdgcn_s_setprio(1);
#pragma unroll
    for (int kk = 0; kk < 2; ++kk)
#pragma unroll
      for (int mi = 0; mi < 4; ++mi)
#pragma unroll
        for (int ni = 0; ni < 4; ++ni)
          acc[mi][ni] = __builtin_amdgcn_mfma_f32_16x16x32_bf16(af[mi][kk], bfr[ni][kk], acc[mi][ni], 0, 0, 0);
    __builtin_amdgcn_s_setprio(0);
    asm volatile("s_barrier" ::: "memory");
    cur ^= 1;
  }
#undef STAGE2

  const int head_base = n0 + wc*64;            // wave's 64 cols = one head
  if (head_base < 2560) {
    // ---- in-thread RoPE: x0 = acc[mi][ni], x1 = acc[mi][ni+2], d = ni*16+sub ----
    const bool isq = (head_base < 2048);
    const float qs = isq ? SCALE_ : 1.0f;
    const float inv0 = exp2f(-0.4152410118609203f * (float)sub);
    const float invs[2] = {inv0, inv0 * 0.01f};  // d and d+16: *10000^(-1/2)
#pragma unroll
    for (int mi = 0; mi < 4; ++mi) {
#pragma unroll
      for (int r = 0; r < 4; ++r) {
        int m = m0 + wr*64 + mi*16 + g*4 + r;
        float p = (float)(pos_ids[m] + 2);
#pragma unroll
        for (int ni = 0; ni < 2; ++ni) {
          int d = ni*16 + sub;
          float f = p * invs[ni], s, c;
          __sincosf(f, &s, &c);
          float x0 = acc[mi][ni][r], x1 = acc[mi][ni+2][r];
          C[(size_t)m * ldc + head_base + d]      = f2b((x0*c - x1*s) * qs);
          C[(size_t)m * ldc + head_base + 32 + d] = f2b((x1*c + x0*s) * qs);
        }
      }
    }
  } else {
#pragma unroll
    for (int mi = 0; mi < 4; ++mi) {
      int rbase = m0 + wr * 64 + mi * 16 + g * 4;
#pragma unroll
      for (int ni = 0; ni < 4; ++ni) {
        int col = head_base + ni*16 + sub;
#pragma unroll
        for (int r = 0; r < 4; ++r)
          C[(size_t)(rbase + r) * ldc + col] = f2b(acc[mi][ni][r]);
      }
    }
  }
}

// ---------------- Wo GEMM: 128x64 tile, BK=64, dbuf (R12-proven), fp32 out ----------------
__global__ __launch_bounds__(256, 3) void gemm_wo(
    const u16* __restrict__ A, const u16* __restrict__ W,
    float* __restrict__ C, int K, int ldc)
{
  __shared__ u16 As[2*128*64];   // 32 KB
  __shared__ u16 Bs[2*64*64];    // 16 KB
  const int m0 = blockIdx.y << 7, n0 = blockIdx.x << 6;
  const int t = threadIdx.x;
  const int wave = t >> 6, lane = t & 63;
  const int wr = wave >> 1, wc = wave & 1;

  f32x4 acc[4][2] = {};

  const int lrow8 = lane >> 3;
  const int lcsw  = ((lane & 7) ^ lrow8) * 8;
  const int fr    = lane & 15;
  const int g     = lane >> 4;
  const int sub   = lane & 15;

#define WSTAGE(BUF, K0) do { \
    _Pragma("unroll") \
    for (int p = 0; p < 4; ++p) { \
      int rbase = p * 32 + wave * 8; \
      GLOAD(A + (size_t)(m0 + rbase + lrow8) * K + (K0) + lcsw, \
            As + (BUF)*8192 + rbase * 64); \
    } \
    _Pragma("unroll") \
    for (int p = 0; p < 2; ++p) { \
      int rbase = p * 32 + wave * 8; \
      GLOAD(W + (size_t)(n0 + rbase + lrow8) * K + (K0) + lcsw, \
            Bs + (BUF)*4096 + rbase * 64); \
    } \
  } while(0)

  WSTAGE(0, 0);
  int cur = 0;
  for (int k0 = 0; k0 < K; k0 += 64) {
    if (k0 + 64 < K) {
      WSTAGE(cur ^ 1, k0 + 64);
      asm volatile("s_waitcnt vmcnt(6)" ::: "memory");
    } else {
      asm volatile("s_waitcnt vmcnt(0)" ::: "memory");
    }
    asm volatile("s_barrier" ::: "memory");

    const u16* Ab = As + cur*8192;
    const u16* Bb = Bs + cur*4096;
    bf16x8 af[4][2], bfr[2][2];
#pragma unroll
    for (int kk = 0; kk < 2; ++kk) {
      int ck = kk * 4 + g;
#pragma unroll
      for (int mi = 0; mi < 4; ++mi) {
        int row = wr * 64 + mi * 16 + fr;
        af[mi][kk] = *(const bf16x8*)(Ab + row * 64 + ((ck ^ (row & 7)) << 3));
      }
#pragma unroll
      for (int ni = 0; ni < 2; ++ni) {
        int row = wc * 16 + ni * 32 + fr;
        bfr[ni][kk] = *(const bf16x8*)(Bb + row * 64 + ((ck ^ (row & 7)) << 3));
      }
    }
    __builtin_amdgcn_s_setprio(1);
#pragma unroll
    for (int kk = 0; kk < 2; ++kk)
#pragma unroll
      for (int mi = 0; mi < 4; ++mi)
#pragma unroll
        for (int ni = 0; ni < 2; ++ni)
          acc[mi][ni] = __builtin_amdgcn_mfma_f32_16x16x32_bf16(af[mi][kk], bfr[ni][kk], acc[mi][ni], 0, 0, 0);
    __builtin_amdgcn_s_setprio(0);
    asm volatile("s_barrier" ::: "memory");
    cur ^= 1;
  }
#undef WSTAGE

#pragma unroll
  for (int mi = 0; mi < 4; ++mi) {
    int rbase = m0 + wr * 64 + mi * 16 + g * 4;
#pragma unroll
    for (int ni = 0; ni < 2; ++ni) {
      int col = n0 + wc*16 + ni*32 + sub;
#pragma unroll
      for (int r = 0; r < 4; ++r)
        C[(size_t)(rbase + r) * ldc + col] = acc[mi][ni][r];
    }
  }
}

// ---------------- MFMA flash attention: QBLK=128, 8 waves, DMA K/V, dbuf (R12) ----------------
__global__ __launch_bounds__(512, 4) void attn_mfma(
    const u16* __restrict__ Yb,         // [M_][3072] bf16, rope applied, q scaled
    const u16* __restrict__ Kb,         // [bh][Q][64] swizzled bf16
    const u16* __restrict__ Vtb,        // [bh][64][Q] swizzled bf16
    const float* __restrict__ cache_k,  // [2][B][H][Q][64] fp32
    const float* __restrict__ cache_v,
    u16* __restrict__ AOb)              // [M_][2048] bf16
{
  __shared__ u16 Qs[128*64];
  __shared__ u16 Ps[128*64];
  __shared__ u16 Ks[2*64*64];
  __shared__ u16 Vt[2*64*64];

  const int bid = blockIdx.x;
  const int xcd = bid & 7, within = bid >> 3;
  const int w8 = within & 7;
  const int qtb = (w8 & 1) ? (7 - (w8 >> 1)) : (w8 >> 1);
  const int pair = xcd * 8 + (within >> 3);
  const int h = pair >> 1, b = pair & 1;
  const int bh = b * H_ + h;

  const int t = threadIdx.x;
  const int wave = t >> 6, lane = t & 63;
  const int g = lane >> 4, sub = lane & 15;
  const int wq0 = wave * 16;
  const int srow = lane >> 3;
  const int scc  = lane & 7;

  const u16* KbT = Kb + (size_t)bh * Q_ * 64;
  const u16* VtT = Vtb + (size_t)bh * 64 * Q_;

#define ATTN_STAGE(BUF, KT) do { \
    int r_ = wave*8 + srow; \
    GLOAD(KbT + (size_t)(((KT)<<6) + r_)*64 + scc*8, Ks + (BUF)*4096 + wave*512); \
    GLOAD(VtT + (size_t)r_*Q_ + ((KT)<<6) + scc*8,   Vt + (BUF)*4096 + wave*512); \
  } while(0)

  {
#pragma unroll
    for (int p = 0; p < 2; ++p) {
      int r = p*64 + wave*8 + srow;
      GLOAD(Yb + (size_t)(b*Q_ + qtb*128 + r)*QKVN_ + h*64 + ((scc ^ (r&7))<<3),
            Qs + p*4096 + wave*512);
    }
  }
  ATTN_STAGE(0, 0);
  asm volatile("s_waitcnt vmcnt(2)" ::: "memory");
  asm volatile("s_barrier" ::: "memory");

  bf16x8 qb[2];
#pragma unroll
  for (int kk = 0; kk < 2; ++kk) {
    int row = wq0 + sub;
    qb[kk] = *(const bf16x8*)&Qs[row*64 + (((4*kk+g) ^ (row&7))<<3)];
  }

  float m_run = -3e38f, l_run = 0.f;
  f32x4 acc_o[4] = {};
  int cur = 0;
  const int nkt = 2*qtb + 2;

  for (int kt = 0; kt < nkt; ++kt) {
    if (kt + 1 < nkt) {
      ATTN_STAGE(cur ^ 1, kt + 1);
      asm volatile("s_waitcnt vmcnt(2)" ::: "memory");
    } else {
      asm volatile("s_waitcnt vmcnt(0)" ::: "memory");
    }
    asm volatile("s_barrier" ::: "memory");

    if (kt*64 <= qtb*128 + wq0 + 15) {
      const u16* ksb = Ks + cur*4096;
      const u16* vtb = Vt + cur*4096;

      f32x4 s[4] = {};
      __builtin_amdgcn_s_setprio(1);
#pragma unroll
      for (int kk = 0; kk < 2; ++kk) {
        int kb = 4*kk + g;
#pragma unroll
        for (int cb = 0; cb < 4; ++cb) {
          int krow = cb*16 + sub;
          bf16x8 kf = *(const bf16x8*)&ksb[krow*64 + ((kb ^ (krow&7))<<3)];
          s[cb] = __builtin_amdgcn_mfma_f32_16x16x32_bf16(kf, qb[kk], s[cb], 0, 0, 0);
        }
      }
      __builtin_amdgcn_s_setprio(0);

      if (kt >= 2*qtb) {
#pragma unroll
        for (int cb = 0; cb < 4; ++cb)
#pragma unroll
          for (int r = 0; r < 4; ++r)
            if (kt*64 + cb*16 + 4*g + r > qtb*128 + wq0 + sub) s[cb][r] = -3e38f;
      }

      float mt = -3e38f;
#pragma unroll
      for (int cb = 0; cb < 4; ++cb)
#pragma unroll
        for (int r = 0; r < 4; ++r) mt = fmaxf(mt, s[cb][r]);
      mt = fmaxf(mt, __shfl_xor(mt, 16, 64));
      mt = fmaxf(mt, __shfl_xor(mt, 32, 64));

      float al = 1.0f;
      if (__any(mt > m_run + 8.f)) {
        float mnew = fmaxf(m_run, mt);
        al = __expf(m_run - mnew);
        m_run = mnew;
        int base = (lane & 48) + ((lane & 48) >> 2);
#pragma unroll
        for (int r = 0; r < 4; ++r) {
          float alr = __shfl(al, base + r, 64);
#pragma unroll
          for (int db = 0; db < 4; ++db) acc_o[db][r] *= alr;
        }
      }

      float sum = 0.f;
#pragma unroll
      for (int cb = 0; cb < 4; ++cb) {
        float p0 = __expf(s[cb][0]-m_run), p1 = __expf(s[cb][1]-m_run);
        float p2 = __expf(s[cb][2]-m_run), p3 = __expf(s[cb][3]-m_run);
        sum += (p0+p1)+(p2+p3);
        unsigned long long pk =
            (unsigned long long)((unsigned int)f2b(p0) | ((unsigned int)f2b(p1)<<16)) |
            ((unsigned long long)((unsigned int)f2b(p2) | ((unsigned int)f2b(p3)<<16)) << 32);
        int col8 = cb*2 + (g>>1);
        int dst = (wq0 + sub)*64 + ((col8 ^ (sub&7))<<3) + ((g&1)<<2);
        *(unsigned long long*)&Ps[dst] = pk;
      }
      sum += __shfl_xor(sum, 16, 64);
      sum += __shfl_xor(sum, 32, 64);
      l_run = l_run*al + sum;

      __builtin_amdgcn_s_setprio(1);
#pragma unroll
      for (int kk = 0; kk < 2; ++kk) {
        bf16x8 pa = *(const bf16x8*)&Ps[(wq0 + sub)*64 + (((4*kk+g) ^ (sub&7))<<3)];
#pragma unroll
        for (int db = 0; db < 4; ++db) {
          int drow = db*16 + sub;
          bf16x8 vf = *(const bf16x8*)&vtb[drow*64 + (((4*kk+g) ^ (drow&7))<<3)];
          acc_o[db] = __builtin_amdgcn_mfma_f32_16x16x32_bf16(pa, vf, acc_o[db], 0, 0, 0);
        }
      }
      __builtin_amdgcn_s_setprio(0);
    }
    asm volatile("s_barrier" ::: "memory");
    cur ^= 1;
  }
#undef ATTN_STAGE

  const int qrow_mine = wq0 + sub;
  const int qpos_mine = qtb*128 + qrow_mine;
  float e1 = 0.f, e2 = 0.f;
  {
    const float* k1p = cache_k + ((size_t)((B_ + b)*H_ + h)*Q_ + qpos_mine)*HD_ + g*16;
    const u16*   kfp = Yb + (size_t)(b*Q_ + qpos_mine)*QKVN_ + H_*HD_ + (h/NREP_)*HD_ + g*16;
    float qv[16];
#pragma unroll
    for (int half = 0; half < 2; ++half) {
      int kb = 2*g + half;
      bf16x8 qq = *(const bf16x8*)&Qs[qrow_mine*64 + ((kb ^ (qrow_mine&7))<<3)];
#pragma unroll
      for (int i = 0; i < 8; ++i) qv[half*8 + i] = b2f(((u16)qq[i]));
    }
    float4 kf4a = *(const float4*)kfp;
    float4 kf4b = *(const float4*)(kfp + 8);
    const u16* kf16a = (const u16*)&kf4a;
    const u16* kf16b = (const u16*)&kf4b;
#pragma unroll
    for (int c = 0; c < 4; ++c) {
      float4 kv1 = *(const float4*)(k1p + 4*c);
      e1 += qv[4*c]*kv1.x + qv[4*c+1]*kv1.y + qv[4*c+2]*kv1.z + qv[4*c+3]*kv1.w;
    }
#pragma unroll
    for (int i = 0; i < 8; ++i) {
      e2 += qv[i]   * b2f(kf16a[i]);
      e2 += qv[8+i] * b2f(kf16b[i]);
    }
  }
  e1 += __shfl_xor(e1, 16, 64); e1 += __shfl_xor(e1, 32, 64);
  e2 += __shfl_xor(e2, 16, 64); e2 += __shfl_xor(e2, 32, 64);

#pragma unroll
  for (int r = 0; r < 4; ++r) {
    int row = 4*g + r;
    int src = (lane & 48) | row;
    float e1r = __shfl(e1, src, 64);
    float e2r = __shfl(e2, src, 64);
    float m_r = __shfl(m_run, src, 64);
    float l_r = __shfl(l_run, src, 64);
    float mnew = fmaxf(m_r, fmaxf(e1r, e2r));
    float alr = __expf(m_r - mnew);
    float w1  = __expf(e1r - mnew);
    float w2  = __expf(e2r - mnew);
    float linv = 1.f / (l_r*alr + w1 + w2);
    int qpos = qtb*128 + wq0 + row;
    const float* v1p = cache_v + ((size_t)((B_ + b)*H_ + h)*Q_ + qpos)*HD_;
    const u16*   vfp = Yb + (size_t)(b*Q_ + qpos)*QKVN_ + (H_*HD_ + KVH_*HD_) + (h/NREP_)*HD_;
    u16* op = AOb + (size_t)(b*Q_ + qpos)*AOW_ + h*HD_;
#pragma unroll
    for (int db = 0; db < 4; ++db) {
      int d = db*16 + sub;
      float o = (acc_o[db][r]*alr + w1*v1p[d] + w2*b2f(vfp[d])) * linv;
      op[d] = f2b(o);
    }
  }
}

extern "C" void kernel_launch(void* const* d_in, const int* in_sizes, int n_in,
                              void* d_out, int out_size, void* d_ws, size_t ws_size,
                              hipStream_t stream) {
  const float* hidden  = (const float*)d_in[0];
  const float* Wq      = (const float*)d_in[1];
  const float* Wk      = (const float*)d_in[2];
  const float* Wv      = (const float*)d_in[3];
  const float* Wo      = (const float*)d_in[4];   // [HS][H*HD]
  const float* cache_k = (const float*)d_in[5];
  const float* cache_v = (const float*)d_in[6];
  const int*   pos_ids = (const int*)d_in[8];
  float* out = (float*)d_out;

  char* ws = (char*)d_ws;
  u16* Yb  = (u16*)ws;  ws += (size_t)M_ * QKVN_ * 2;
  u16* Xb  = (u16*)ws;  ws += (size_t)M_ * KIN_ * 2;
  u16* Wb  = (u16*)ws;  ws += (size_t)QKVN_ * KIN_ * 2;
  u16* Wob = (u16*)ws;  ws += (size_t)HS_ * AOW_ * 2;
  u16* Kb  = (u16*)ws;  ws += (size_t)B_*H_*Q_*64 * 2;
  u16* Vtb = (u16*)ws;  ws += (size_t)B_*H_*Q_*64 * 2;
  u16* AOb = Xb;                                           // Xb dead after QKV GEMM

  prep_kernel<<<dim3(3072), 256, 0, stream>>>(
      hidden, Wq, Wk, Wv, Wo, cache_k, cache_v, Xb, Wb, Wob, Kb, Vtb);

  // QKV GEMM (128x128 tile) with fused in-thread RoPE: grid 24x16 = 384 blocks
  gemm_qkv<<<dim3(QKVN_/128, M_/128), 256, 0, stream>>>(Xb, Wb, Yb, KIN_, QKVN_, pos_ids);
  // attention: 512 blocks x 512 threads
  attn_mfma<<<dim3(512), 512, 0, stream>>>(Yb, Kb, Vtb, cache_k, cache_v, AOb);
  // Wo GEMM (128x64 tile, R12-proven): grid 32x16 = 512 blocks, fp32 out
  gemm_wo<<<dim3(HS_/64, M_/128), 256, 0, stream>>>(AOb, Wob, out, AOW_, HS_);
}

// Round 15
// 165.009 us; speedup vs baseline: 1.3764x; 1.0367x over previous
//
#include <hip/hip_runtime.h>
#include <hip/hip_bf16.h>
#include <math.h>

#define B_    2
#define Q_    1024
#define H_    32
#define KVH_  8
#define HD_   64
#define HS_   2048
#define NREP_ 4
#define KIN_  (2*HS_)            // 4096
#define M_    (B_*Q_)            // 2048
#define QKVN_ (H_*HD_ + 2*KVH_*HD_)  // 3072
#define AOW_  (H_*HD_)           // 2048
#define SCALE_ 0.125f            // 1/sqrt(64)

typedef __attribute__((ext_vector_type(8))) short bf16x8;
typedef __attribute__((ext_vector_type(4))) float f32x4;
typedef unsigned short u16;

static __device__ __forceinline__ u16 f2b(float f) {
  union { float f; unsigned int u; } c; c.f = f;
  unsigned int r = (c.u + 0x7fffu + ((c.u >> 16) & 1u)) >> 16;
  return (u16)r;
}
static __device__ __forceinline__ float b2f(u16 s) {
  union { unsigned int u; float f; } c;
  c.u = ((unsigned int)s) << 16;
  return c.f;
}
static __device__ __forceinline__ unsigned long long pack4s(float4 v, float sc) {
  return (unsigned long long)f2b(v.x*sc) |
         ((unsigned long long)f2b(v.y*sc) << 16) |
         ((unsigned long long)f2b(v.z*sc) << 32) |
         ((unsigned long long)f2b(v.w*sc) << 48);
}

#define GLOAD(SRC, DST) __builtin_amdgcn_global_load_lds( \
    (const __attribute__((address_space(1))) void*)(SRC), \
    (__attribute__((address_space(3))) void*)(DST), 16, 0, 0)

// ---------------- merged prep: K/V transpose-cast (blocks 0..1023) + flat casts ----------------
__global__ __launch_bounds__(256) void prep_kernel(
    const float* __restrict__ hidden, const float* __restrict__ Wq,
    const float* __restrict__ Wk, const float* __restrict__ Wv,
    const float* __restrict__ Wo,
    const float* __restrict__ k0, const float* __restrict__ v0,
    u16* __restrict__ Xb, u16* __restrict__ Wb, u16* __restrict__ Wob,
    u16* __restrict__ Kb, u16* __restrict__ Vtb)
{
  __shared__ float Vs[64][65];
  const int bx = blockIdx.x;
  const int t = threadIdx.x;
  if (bx < 1024) {
    const int kt = bx & 15, bh = bx >> 4;
    const int r = t >> 2, seg = t & 3;
    {
      const float* sp = k0 + ((size_t)bh*Q_ + (kt<<6) + r)*64;
      u16* dp = Kb + ((size_t)bh*Q_ + (kt<<6) + r)*64;
#pragma unroll
      for (int c2 = 2*seg; c2 < 2*seg+2; ++c2) {
        int ca = c2 ^ (r & 7);
        float4 a = *(const float4*)(sp + ca*8);
        float4 b = *(const float4*)(sp + ca*8 + 4);
        unsigned long long o[2] = {pack4s(a,1.f), pack4s(b,1.f)};
        *(float4*)(dp + c2*8) = *(const float4*)o;
      }
    }
    {
      const float* sp = v0 + ((size_t)bh*Q_ + (kt<<6) + r)*64 + seg*16;
#pragma unroll
      for (int c = 0; c < 4; ++c) {
        float4 v = *(const float4*)(sp + 4*c);
        Vs[r][seg*16 + 4*c + 0] = v.x; Vs[r][seg*16 + 4*c + 1] = v.y;
        Vs[r][seg*16 + 4*c + 2] = v.z; Vs[r][seg*16 + 4*c + 3] = v.w;
      }
    }
    __syncthreads();
    {
      const int d = r;
      u16* dp = Vtb + ((size_t)bh*64 + d)*Q_ + (kt<<6);
#pragma unroll
      for (int c2 = 2*seg; c2 < 2*seg+2; ++c2) {
        int ca = c2 ^ (d & 7);
        u16 o[8];
#pragma unroll
        for (int j = 0; j < 8; ++j) o[j] = f2b(Vs[ca*8 + j][d]);
        *(float4*)(dp + c2*8) = *(const float4*)o;
      }
    }
  } else {
    const int U0 = 1048576;
    const int U1 = U0 + 1048576;
    const int U2 = U1 + 262144;
    const int U3 = U2 + 262144;
    const int U4 = U3 + 524288;
    for (int u = (bx - 1024)*256 + t; u < U4; u += 2048*256) {
      const float* src; u16* dst;
      if (u < U0)      { src = hidden + (size_t)u*8;   dst = Xb + (size_t)u*8; }
      else if (u < U1) { src = Wq + (size_t)(u-U0)*8;  dst = Wb + (size_t)(u-U0)*8; }
      else if (u < U2) { src = Wk + (size_t)(u-U1)*8;  dst = Wb + (size_t)2048*KIN_ + (size_t)(u-U1)*8; }
      else if (u < U3) { src = Wv + (size_t)(u-U2)*8;  dst = Wb + (size_t)2560*KIN_ + (size_t)(u-U2)*8; }
      else             { src = Wo + (size_t)(u-U3)*8;  dst = Wob + (size_t)(u-U3)*8; }
      float4 a = *(const float4*)src;
      float4 bb = *(const float4*)(src + 4);
      unsigned long long o[2] = {pack4s(a, 1.f), pack4s(bb, 1.f)};
      *(float4*)dst = *(const float4*)o;
    }
  }
}

// ---------------- bf16 NT MFMA GEMM, 128x64, BK=64, dbuf; in-thread RoPE epilogue ----------------
// (R12-proven: 68 us QKV, 0 bank conflicts.)  B-fragment columns per wave:
// {wc*16+sub, 32+wc*16+sub} so the RoPE pair (d, d+32) = (acc[mi][0], acc[mi][1]).
template<bool QKV>
__global__ __launch_bounds__(256, 3) void gemm_nt(
    const u16* __restrict__ A, const u16* __restrict__ W,
    void* __restrict__ Cv, int K, int ldc, const int* __restrict__ pos_ids)
{
  __shared__ u16 As[2*128*64];   // 32 KB
  __shared__ u16 Bs[2*64*64];    // 16 KB
  const int m0 = blockIdx.y << 7, n0 = blockIdx.x << 6;
  const int t = threadIdx.x;
  const int wave = t >> 6, lane = t & 63;
  const int wr = wave >> 1, wc = wave & 1;

  f32x4 acc[4][2] = {};

  const int lrow8 = lane >> 3;
  const int lcsw  = ((lane & 7) ^ lrow8) * 8;
  const int fr    = lane & 15;
  const int g     = lane >> 4;
  const int sub   = lane & 15;

#define GEMM_STAGE(BUF, K0) do { \
    _Pragma("unroll") \
    for (int p = 0; p < 4; ++p) { \
      int rbase = p * 32 + wave * 8; \
      GLOAD(A + (size_t)(m0 + rbase + lrow8) * K + (K0) + lcsw, \
            As + (BUF)*8192 + rbase * 64); \
    } \
    _Pragma("unroll") \
    for (int p = 0; p < 2; ++p) { \
      int rbase = p * 32 + wave * 8; \
      GLOAD(W + (size_t)(n0 + rbase + lrow8) * K + (K0) + lcsw, \
            Bs + (BUF)*4096 + rbase * 64); \
    } \
  } while(0)

  GEMM_STAGE(0, 0);
  int cur = 0;
  for (int k0 = 0; k0 < K; k0 += 64) {
    if (k0 + 64 < K) {
      GEMM_STAGE(cur ^ 1, k0 + 64);
      asm volatile("s_waitcnt vmcnt(6)" ::: "memory");
    } else {
      asm volatile("s_waitcnt vmcnt(0)" ::: "memory");
    }
    asm volatile("s_barrier" ::: "memory");

    const u16* Ab = As + cur*8192;
    const u16* Bb = Bs + cur*4096;
    bf16x8 af[4][2], bfr[2][2];
#pragma unroll
    for (int kk = 0; kk < 2; ++kk) {
      int ck = kk * 4 + g;
#pragma unroll
      for (int mi = 0; mi < 4; ++mi) {
        int row = wr * 64 + mi * 16 + fr;
        af[mi][kk] = *(const bf16x8*)(Ab + row * 64 + ((ck ^ (row & 7)) << 3));
      }
#pragma unroll
      for (int ni = 0; ni < 2; ++ni) {
        int row = wc * 16 + ni * 32 + fr;     // cols {wc*16+sub, 32+wc*16+sub}
        bfr[ni][kk] = *(const bf16x8*)(Bb + row * 64 + ((ck ^ (row & 7)) << 3));
      }
    }
    __builtin_amdgcn_s_setprio(1);
#pragma unroll
    for (int kk = 0; kk < 2; ++kk)
#pragma unroll
      for (int mi = 0; mi < 4; ++mi)
#pragma unroll
        for (int ni = 0; ni < 2; ++ni)
          acc[mi][ni] = __builtin_amdgcn_mfma_f32_16x16x32_bf16(af[mi][kk], bfr[ni][kk], acc[mi][ni], 0, 0, 0);
    __builtin_amdgcn_s_setprio(0);
    asm volatile("s_barrier" ::: "memory");
    cur ^= 1;
  }
#undef GEMM_STAGE

  if (QKV && n0 < 2560) {
    // ---- in-thread RoPE epilogue: pair = (acc[mi][0], acc[mi][1]) ----
    u16* outp = (u16*)Cv;
    const bool isq = (n0 < 2048);
    const float qs = isq ? SCALE_ : 1.0f;
    const int d = wc*16 + sub;                  // freq index 0..31
    const float inv = exp2f(-0.4152410118609203f * (float)d);
#pragma unroll
    for (int mi = 0; mi < 4; ++mi) {
#pragma unroll
      for (int r = 0; r < 4; ++r) {
        int m = m0 + wr*64 + mi*16 + g*4 + r;
        float p = (float)(pos_ids[m] + 2);
        float f = p * inv, s, c;
        __sincosf(f, &s, &c);
        float x0 = acc[mi][0][r], x1 = acc[mi][1][r];
        outp[(size_t)m * ldc + n0 + d]      = f2b((x0*c - x1*s) * qs);
        outp[(size_t)m * ldc + n0 + 32 + d] = f2b((x1*c + x0*s) * qs);
      }
    }
  } else {
#pragma unroll
    for (int mi = 0; mi < 4; ++mi) {
      int rbase = m0 + wr * 64 + mi * 16 + g * 4;
#pragma unroll
      for (int ni = 0; ni < 2; ++ni) {
        int col = n0 + wc*16 + ni*32 + sub;
#pragma unroll
        for (int r = 0; r < 4; ++r) {
          if (QKV) ((u16*)Cv)[(size_t)(rbase + r) * ldc + col] = f2b(acc[mi][ni][r]);
          else     ((float*)Cv)[(size_t)(rbase + r) * ldc + col] = acc[mi][ni][r];
        }
      }
    }
  }
}

// ---------------- MFMA flash attention: QBLK=128, 8 waves, K/V triple-buffer 2-deep ----------------
__global__ __launch_bounds__(512, 4) void attn_mfma(
    const u16* __restrict__ Yb,         // [M_][3072] bf16, rope applied, q scaled
    const u16* __restrict__ Kb,         // [bh][Q][64] swizzled bf16
    const u16* __restrict__ Vtb,        // [bh][64][Q] swizzled bf16
    const float* __restrict__ cache_k,  // [2][B][H][Q][64] fp32
    const float* __restrict__ cache_v,
    u16* __restrict__ AOb)              // [M_][2048] bf16
{
  __shared__ u16 Qs[128*64];   // 16 KB
  __shared__ u16 Ps[128*64];   // 16 KB
  __shared__ u16 Ks[3*64*64];  // 24 KB  (3 buffers, 2-deep prefetch)
  __shared__ u16 Vt[3*64*64];  // 24 KB  (total 80 KB, 2 blocks/CU)

  const int bid = blockIdx.x;
  const int xcd = bid & 7, within = bid >> 3;
  const int w8 = within & 7;
  const int qtb = (w8 & 1) ? (7 - (w8 >> 1)) : (w8 >> 1);
  const int pair = xcd * 8 + (within >> 3);
  const int h = pair >> 1, b = pair & 1;
  const int bh = b * H_ + h;

  const int t = threadIdx.x;
  const int wave = t >> 6, lane = t & 63;
  const int g = lane >> 4, sub = lane & 15;
  const int wq0 = wave * 16;
  const int srow = lane >> 3;
  const int scc  = lane & 7;

  const u16* KbT = Kb + (size_t)bh * Q_ * 64;
  const u16* VtT = Vtb + (size_t)bh * 64 * Q_;

#define ATTN_STAGE(BUF, KT) do { \
    int r_ = wave*8 + srow; \
    GLOAD(KbT + (size_t)(((KT)<<6) + r_)*64 + scc*8, Ks + (BUF)*4096 + wave*512); \
    GLOAD(VtT + (size_t)r_*Q_ + ((KT)<<6) + scc*8,   Vt + (BUF)*4096 + wave*512); \
  } while(0)

  const int nkt = 2*qtb + 2;     // >= 2 always

  {  // stage Q (2 loads) + tiles 0,1
#pragma unroll
    for (int p = 0; p < 2; ++p) {
      int r = p*64 + wave*8 + srow;
      GLOAD(Yb + (size_t)(b*Q_ + qtb*128 + r)*QKVN_ + h*64 + ((scc ^ (r&7))<<3),
            Qs + p*4096 + wave*512);
    }
  }
  ATTN_STAGE(0, 0);
  ATTN_STAGE(1, 1);
  asm volatile("s_waitcnt vmcnt(2)" ::: "memory");   // Q + tile0 done; tile1 in flight
  asm volatile("s_barrier" ::: "memory");

  bf16x8 qb[2];
#pragma unroll
  for (int kk = 0; kk < 2; ++kk) {
    int row = wq0 + sub;
    qb[kk] = *(const bf16x8*)&Qs[row*64 + (((4*kk+g) ^ (row&7))<<3)];
  }

  float m_run = -3e38f, l_run = 0.f;
  f32x4 acc_o[4] = {};

  for (int kt = 0; kt < nkt; ++kt) {
    if (kt + 2 < nkt) {
      ATTN_STAGE((kt + 2) % 3, kt + 2);
      asm volatile("s_waitcnt vmcnt(4)" ::: "memory");   // tile kt done; kt+1,kt+2 in flight
    } else if (kt + 1 < nkt) {
      asm volatile("s_waitcnt vmcnt(2)" ::: "memory");   // tile kt done; kt+1 in flight
    } else {
      asm volatile("s_waitcnt vmcnt(0)" ::: "memory");
    }
    asm volatile("s_barrier" ::: "memory");

    if (kt*64 <= qtb*128 + wq0 + 15) {
      const int cb3 = kt % 3;
      const u16* ksb = Ks + cb3*4096;
      const u16* vtb = Vt + cb3*4096;

      f32x4 s[4] = {};
      __builtin_amdgcn_s_setprio(1);
#pragma unroll
      for (int kk = 0; kk < 2; ++kk) {
        int kb = 4*kk + g;
#pragma unroll
        for (int cb = 0; cb < 4; ++cb) {
          int krow = cb*16 + sub;
          bf16x8 kf = *(const bf16x8*)&ksb[krow*64 + ((kb ^ (krow&7))<<3)];
          s[cb] = __builtin_amdgcn_mfma_f32_16x16x32_bf16(kf, qb[kk], s[cb], 0, 0, 0);
        }
      }
      __builtin_amdgcn_s_setprio(0);

      if (kt >= 2*qtb) {
#pragma unroll
        for (int cb = 0; cb < 4; ++cb)
#pragma unroll
          for (int r = 0; r < 4; ++r)
            if (kt*64 + cb*16 + 4*g + r > qtb*128 + wq0 + sub) s[cb][r] = -3e38f;
      }

      float mt = -3e38f;
#pragma unroll
      for (int cb = 0; cb < 4; ++cb)
#pragma unroll
        for (int r = 0; r < 4; ++r) mt = fmaxf(mt, s[cb][r]);
      mt = fmaxf(mt, __shfl_xor(mt, 16, 64));
      mt = fmaxf(mt, __shfl_xor(mt, 32, 64));

      float al = 1.0f;
      if (__any(mt > m_run + 8.f)) {
        float mnew = fmaxf(m_run, mt);
        al = __expf(m_run - mnew);
        m_run = mnew;
        int base = (lane & 48) + ((lane & 48) >> 2);
#pragma unroll
        for (int r = 0; r < 4; ++r) {
          float alr = __shfl(al, base + r, 64);
#pragma unroll
          for (int db = 0; db < 4; ++db) acc_o[db][r] *= alr;
        }
      }

      float sum = 0.f;
#pragma unroll
      for (int cb = 0; cb < 4; ++cb) {
        float p0 = __expf(s[cb][0]-m_run), p1 = __expf(s[cb][1]-m_run);
        float p2 = __expf(s[cb][2]-m_run), p3 = __expf(s[cb][3]-m_run);
        sum += (p0+p1)+(p2+p3);
        unsigned long long pk =
            (unsigned long long)((unsigned int)f2b(p0) | ((unsigned int)f2b(p1)<<16)) |
            ((unsigned long long)((unsigned int)f2b(p2) | ((unsigned int)f2b(p3)<<16)) << 32);
        int col8 = cb*2 + (g>>1);
        int dst = (wq0 + sub)*64 + ((col8 ^ (sub&7))<<3) + ((g&1)<<2);
        *(unsigned long long*)&Ps[dst] = pk;
      }
      sum += __shfl_xor(sum, 16, 64);
      sum += __shfl_xor(sum, 32, 64);
      l_run = l_run*al + sum;

      __builtin_amdgcn_s_setprio(1);
#pragma unroll
      for (int kk = 0; kk < 2; ++kk) {
        bf16x8 pa = *(const bf16x8*)&Ps[(wq0 + sub)*64 + (((4*kk+g) ^ (sub&7))<<3)];
#pragma unroll
        for (int db = 0; db < 4; ++db) {
          int drow = db*16 + sub;
          bf16x8 vf = *(const bf16x8*)&vtb[drow*64 + (((4*kk+g) ^ (drow&7))<<3)];
          acc_o[db] = __builtin_amdgcn_mfma_f32_16x16x32_bf16(pa, vf, acc_o[db], 0, 0, 0);
        }
      }
      __builtin_amdgcn_s_setprio(0);
    }
    asm volatile("s_barrier" ::: "memory");
  }
#undef ATTN_STAGE

  const int qrow_mine = wq0 + sub;
  const int qpos_mine = qtb*128 + qrow_mine;
  float e1 = 0.f, e2 = 0.f;
  {
    const float* k1p = cache_k + ((size_t)((B_ + b)*H_ + h)*Q_ + qpos_mine)*HD_ + g*16;
    const u16*   kfp = Yb + (size_t)(b*Q_ + qpos_mine)*QKVN_ + H_*HD_ + (h/NREP_)*HD_ + g*16;
    float qv[16];
#pragma unroll
    for (int half = 0; half < 2; ++half) {
      int kb = 2*g + half;
      bf16x8 qq = *(const bf16x8*)&Qs[qrow_mine*64 + ((kb ^ (qrow_mine&7))<<3)];
#pragma unroll
      for (int i = 0; i < 8; ++i) qv[half*8 + i] = b2f(((u16)qq[i]));
    }
    float4 kf4a = *(const float4*)kfp;
    float4 kf4b = *(const float4*)(kfp + 8);
    const u16* kf16a = (const u16*)&kf4a;
    const u16* kf16b = (const u16*)&kf4b;
#pragma unroll
    for (int c = 0; c < 4; ++c) {
      float4 kv1 = *(const float4*)(k1p + 4*c);
      e1 += qv[4*c]*kv1.x + qv[4*c+1]*kv1.y + qv[4*c+2]*kv1.z + qv[4*c+3]*kv1.w;
    }
#pragma unroll
    for (int i = 0; i < 8; ++i) {
      e2 += qv[i]   * b2f(kf16a[i]);
      e2 += qv[8+i] * b2f(kf16b[i]);
    }
  }
  e1 += __shfl_xor(e1, 16, 64); e1 += __shfl_xor(e1, 32, 64);
  e2 += __shfl_xor(e2, 16, 64); e2 += __shfl_xor(e2, 32, 64);

#pragma unroll
  for (int r = 0; r < 4; ++r) {
    int row = 4*g + r;
    int src = (lane & 48) | row;
    float e1r = __shfl(e1, src, 64);
    float e2r = __shfl(e2, src, 64);
    float m_r = __shfl(m_run, src, 64);
    float l_r = __shfl(l_run, src, 64);
    float mnew = fmaxf(m_r, fmaxf(e1r, e2r));
    float alr = __expf(m_r - mnew);
    float w1  = __expf(e1r - mnew);
    float w2  = __expf(e2r - mnew);
    float linv = 1.f / (l_r*alr + w1 + w2);
    int qpos = qtb*128 + wq0 + row;
    const float* v1p = cache_v + ((size_t)((B_ + b)*H_ + h)*Q_ + qpos)*HD_;
    const u16*   vfp = Yb + (size_t)(b*Q_ + qpos)*QKVN_ + (H_*HD_ + KVH_*HD_) + (h/NREP_)*HD_;
    u16* op = AOb + (size_t)(b*Q_ + qpos)*AOW_ + h*HD_;
#pragma unroll
    for (int db = 0; db < 4; ++db) {
      int d = db*16 + sub;
      float o = (acc_o[db][r]*alr + w1*v1p[d] + w2*b2f(vfp[d])) * linv;
      op[d] = f2b(o);
    }
  }
}

extern "C" void kernel_launch(void* const* d_in, const int* in_sizes, int n_in,
                              void* d_out, int out_size, void* d_ws, size_t ws_size,
                              hipStream_t stream) {
  const float* hidden  = (const float*)d_in[0];
  const float* Wq      = (const float*)d_in[1];
  const float* Wk      = (const float*)d_in[2];
  const float* Wv      = (const float*)d_in[3];
  const float* Wo      = (const float*)d_in[4];   // [HS][H*HD]
  const float* cache_k = (const float*)d_in[5];
  const float* cache_v = (const float*)d_in[6];
  const int*   pos_ids = (const int*)d_in[8];
  float* out = (float*)d_out;

  char* ws = (char*)d_ws;
  u16* Yb  = (u16*)ws;  ws += (size_t)M_ * QKVN_ * 2;
  u16* Xb  = (u16*)ws;  ws += (size_t)M_ * KIN_ * 2;
  u16* Wb  = (u16*)ws;  ws += (size_t)QKVN_ * KIN_ * 2;
  u16* Wob = (u16*)ws;  ws += (size_t)HS_ * AOW_ * 2;
  u16* Kb  = (u16*)ws;  ws += (size_t)B_*H_*Q_*64 * 2;
  u16* Vtb = (u16*)ws;  ws += (size_t)B_*H_*Q_*64 * 2;
  u16* AOb = Xb;                                           // Xb dead after QKV GEMM

  prep_kernel<<<dim3(3072), 256, 0, stream>>>(
      hidden, Wq, Wk, Wv, Wo, cache_k, cache_v, Xb, Wb, Wob, Kb, Vtb);

  // QKV GEMM with fused in-thread RoPE epilogue: grid 48x16 = 768 blocks
  gemm_nt<true><<<dim3(QKVN_/64, M_/128), 256, 0, stream>>>(Xb, Wb, (void*)Yb, KIN_, QKVN_, pos_ids);
  // attention: 512 blocks x 512 threads
  attn_mfma<<<dim3(512), 512, 0, stream>>>(Yb, Kb, Vtb, cache_k, cache_v, AOb);
  // Wo GEMM: grid 32x16 = 512 blocks, fp32 out
  gemm_nt<false><<<dim3(HS_/64, M_/128), 256, 0, stream>>>(AOb, Wob, (void*)out, AOW_, HS_, nullptr);
}

// Round 16
// 160.666 us; speedup vs baseline: 1.4136x; 1.0270x over previous
//
#include <hip/hip_runtime.h>
#include <hip/hip_bf16.h>
#include <math.h>

#define B_    2
#define Q_    1024
#define H_    32
#define KVH_  8
#define HD_   64
#define HS_   2048
#define NREP_ 4
#define KIN_  (2*HS_)            // 4096
#define M_    (B_*Q_)            // 2048
#define QKVN_ (H_*HD_ + 2*KVH_*HD_)  // 3072
#define AOW_  (H_*HD_)           // 2048
#define SCALE_ 0.125f            // 1/sqrt(64)

typedef __attribute__((ext_vector_type(8))) short bf16x8;
typedef __attribute__((ext_vector_type(4))) float f32x4;
typedef unsigned short u16;

static __device__ __forceinline__ u16 f2b(float f) {
  union { float f; unsigned int u; } c; c.f = f;
  unsigned int r = (c.u + 0x7fffu + ((c.u >> 16) & 1u)) >> 16;
  return (u16)r;
}
static __device__ __forceinline__ float b2f(u16 s) {
  union { unsigned int u; float f; } c;
  c.u = ((unsigned int)s) << 16;
  return c.f;
}
static __device__ __forceinline__ unsigned long long pack4s(float4 v, float sc) {
  return (unsigned long long)f2b(v.x*sc) |
         ((unsigned long long)f2b(v.y*sc) << 16) |
         ((unsigned long long)f2b(v.z*sc) << 32) |
         ((unsigned long long)f2b(v.w*sc) << 48);
}

#define GLOAD(SRC, DST) __builtin_amdgcn_global_load_lds( \
    (const __attribute__((address_space(1))) void*)(SRC), \
    (__attribute__((address_space(3))) void*)(DST), 16, 0, 0)

// ---------------- merged prep: K/V transpose-cast (blocks 0..1023) + flat casts ----------------
__global__ __launch_bounds__(256) void prep_kernel(
    const float* __restrict__ hidden, const float* __restrict__ Wq,
    const float* __restrict__ Wk, const float* __restrict__ Wv,
    const float* __restrict__ Wo,
    const float* __restrict__ k0, const float* __restrict__ v0,
    u16* __restrict__ Xb, u16* __restrict__ Wb, u16* __restrict__ Wob,
    u16* __restrict__ Kb, u16* __restrict__ Vtb)
{
  __shared__ float Vs[64][65];
  const int bx = blockIdx.x;
  const int t = threadIdx.x;
  if (bx < 1024) {
    const int kt = bx & 15, bh = bx >> 4;
    const int r = t >> 2, seg = t & 3;
    {
      const float* sp = k0 + ((size_t)bh*Q_ + (kt<<6) + r)*64;
      u16* dp = Kb + ((size_t)bh*Q_ + (kt<<6) + r)*64;
#pragma unroll
      for (int c2 = 2*seg; c2 < 2*seg+2; ++c2) {
        int ca = c2 ^ (r & 7);
        float4 a = *(const float4*)(sp + ca*8);
        float4 b = *(const float4*)(sp + ca*8 + 4);
        unsigned long long o[2] = {pack4s(a,1.f), pack4s(b,1.f)};
        *(float4*)(dp + c2*8) = *(const float4*)o;
      }
    }
    {
      const float* sp = v0 + ((size_t)bh*Q_ + (kt<<6) + r)*64 + seg*16;
#pragma unroll
      for (int c = 0; c < 4; ++c) {
        float4 v = *(const float4*)(sp + 4*c);
        Vs[r][seg*16 + 4*c + 0] = v.x; Vs[r][seg*16 + 4*c + 1] = v.y;
        Vs[r][seg*16 + 4*c + 2] = v.z; Vs[r][seg*16 + 4*c + 3] = v.w;
      }
    }
    __syncthreads();
    {
      const int d = r;
      u16* dp = Vtb + ((size_t)bh*64 + d)*Q_ + (kt<<6);
#pragma unroll
      for (int c2 = 2*seg; c2 < 2*seg+2; ++c2) {
        int ca = c2 ^ (d & 7);
        u16 o[8];
#pragma unroll
        for (int j = 0; j < 8; ++j) o[j] = f2b(Vs[ca*8 + j][d]);
        *(float4*)(dp + c2*8) = *(const float4*)o;
      }
    }
  } else {
    const int U0 = 1048576;
    const int U1 = U0 + 1048576;
    const int U2 = U1 + 262144;
    const int U3 = U2 + 262144;
    const int U4 = U3 + 524288;
    for (int u = (bx - 1024)*256 + t; u < U4; u += 2048*256) {
      const float* src; u16* dst;
      if (u < U0)      { src = hidden + (size_t)u*8;   dst = Xb + (size_t)u*8; }
      else if (u < U1) { src = Wq + (size_t)(u-U0)*8;  dst = Wb + (size_t)(u-U0)*8; }
      else if (u < U2) { src = Wk + (size_t)(u-U1)*8;  dst = Wb + (size_t)2048*KIN_ + (size_t)(u-U1)*8; }
      else if (u < U3) { src = Wv + (size_t)(u-U2)*8;  dst = Wb + (size_t)2560*KIN_ + (size_t)(u-U2)*8; }
      else             { src = Wo + (size_t)(u-U3)*8;  dst = Wob + (size_t)(u-U3)*8; }
      float4 a = *(const float4*)src;
      float4 bb = *(const float4*)(src + 4);
      unsigned long long o[2] = {pack4s(a, 1.f), pack4s(bb, 1.f)};
      *(float4*)dst = *(const float4*)o;
    }
  }
}

// ---------------- bf16 NT MFMA GEMM, 128x64, BK=64, dbuf; in-thread RoPE epilogue ----------------
// (Measured best: 68 us QKV, 0 bank conflicts, MfmaUtil ~33%.)  B-fragment columns
// per wave: {wc*16+sub, 32+wc*16+sub} so RoPE pair (d, d+32) = (acc[mi][0], acc[mi][1]).
template<bool QKV>
__global__ __launch_bounds__(256, 3) void gemm_nt(
    const u16* __restrict__ A, const u16* __restrict__ W,
    void* __restrict__ Cv, int K, int ldc, const int* __restrict__ pos_ids)
{
  __shared__ u16 As[2*128*64];   // 32 KB
  __shared__ u16 Bs[2*64*64];    // 16 KB
  const int m0 = blockIdx.y << 7, n0 = blockIdx.x << 6;
  const int t = threadIdx.x;
  const int wave = t >> 6, lane = t & 63;
  const int wr = wave >> 1, wc = wave & 1;

  f32x4 acc[4][2] = {};

  const int lrow8 = lane >> 3;
  const int lcsw  = ((lane & 7) ^ lrow8) * 8;
  const int fr    = lane & 15;
  const int g     = lane >> 4;
  const int sub   = lane & 15;

#define GEMM_STAGE(BUF, K0) do { \
    _Pragma("unroll") \
    for (int p = 0; p < 4; ++p) { \
      int rbase = p * 32 + wave * 8; \
      GLOAD(A + (size_t)(m0 + rbase + lrow8) * K + (K0) + lcsw, \
            As + (BUF)*8192 + rbase * 64); \
    } \
    _Pragma("unroll") \
    for (int p = 0; p < 2; ++p) { \
      int rbase = p * 32 + wave * 8; \
      GLOAD(W + (size_t)(n0 + rbase + lrow8) * K + (K0) + lcsw, \
            Bs + (BUF)*4096 + rbase * 64); \
    } \
  } while(0)

  GEMM_STAGE(0, 0);
  int cur = 0;
  for (int k0 = 0; k0 < K; k0 += 64) {
    if (k0 + 64 < K) {
      GEMM_STAGE(cur ^ 1, k0 + 64);
      asm volatile("s_waitcnt vmcnt(6)" ::: "memory");
    } else {
      asm volatile("s_waitcnt vmcnt(0)" ::: "memory");
    }
    asm volatile("s_barrier" ::: "memory");

    const u16* Ab = As + cur*8192;
    const u16* Bb = Bs + cur*4096;
    bf16x8 af[4][2], bfr[2][2];
#pragma unroll
    for (int kk = 0; kk < 2; ++kk) {
      int ck = kk * 4 + g;
#pragma unroll
      for (int mi = 0; mi < 4; ++mi) {
        int row = wr * 64 + mi * 16 + fr;
        af[mi][kk] = *(const bf16x8*)(Ab + row * 64 + ((ck ^ (row & 7)) << 3));
      }
#pragma unroll
      for (int ni = 0; ni < 2; ++ni) {
        int row = wc * 16 + ni * 32 + fr;     // cols {wc*16+sub, 32+wc*16+sub}
        bfr[ni][kk] = *(const bf16x8*)(Bb + row * 64 + ((ck ^ (row & 7)) << 3));
      }
    }
    __builtin_amdgcn_s_setprio(1);
#pragma unroll
    for (int kk = 0; kk < 2; ++kk)
#pragma unroll
      for (int mi = 0; mi < 4; ++mi)
#pragma unroll
        for (int ni = 0; ni < 2; ++ni)
          acc[mi][ni] = __builtin_amdgcn_mfma_f32_16x16x32_bf16(af[mi][kk], bfr[ni][kk], acc[mi][ni], 0, 0, 0);
    __builtin_amdgcn_s_setprio(0);
    asm volatile("s_barrier" ::: "memory");
    cur ^= 1;
  }
#undef GEMM_STAGE

  if (QKV && n0 < 2560) {
    // ---- in-thread RoPE epilogue: pair = (acc[mi][0], acc[mi][1]) ----
    u16* outp = (u16*)Cv;
    const bool isq = (n0 < 2048);
    const float qs = isq ? SCALE_ : 1.0f;
    const int d = wc*16 + sub;                  // freq index 0..31
    const float inv = exp2f(-0.4152410118609203f * (float)d);
#pragma unroll
    for (int mi = 0; mi < 4; ++mi) {
#pragma unroll
      for (int r = 0; r < 4; ++r) {
        int m = m0 + wr*64 + mi*16 + g*4 + r;
        float p = (float)(pos_ids[m] + 2);
        float f = p * inv, s, c;
        __sincosf(f, &s, &c);
        float x0 = acc[mi][0][r], x1 = acc[mi][1][r];
        outp[(size_t)m * ldc + n0 + d]      = f2b((x0*c - x1*s) * qs);
        outp[(size_t)m * ldc + n0 + 32 + d] = f2b((x1*c + x0*s) * qs);
      }
    }
  } else {
#pragma unroll
    for (int mi = 0; mi < 4; ++mi) {
      int rbase = m0 + wr * 64 + mi * 16 + g * 4;
#pragma unroll
      for (int ni = 0; ni < 2; ++ni) {
        int col = n0 + wc*16 + ni*32 + sub;
#pragma unroll
        for (int r = 0; r < 4; ++r) {
          if (QKV) ((u16*)Cv)[(size_t)(rbase + r) * ldc + col] = f2b(acc[mi][ni][r]);
          else     ((float*)Cv)[(size_t)(rbase + r) * ldc + col] = acc[mi][ni][r];
        }
      }
    }
  }
}

// ---------------- MFMA flash attention: QBLK=128, 8 waves, DMA K/V, dbuf ----------------
__global__ __launch_bounds__(512, 4) void attn_mfma(
    const u16* __restrict__ Yb,         // [M_][3072] bf16, rope applied, q scaled
    const u16* __restrict__ Kb,         // [bh][Q][64] swizzled bf16
    const u16* __restrict__ Vtb,        // [bh][64][Q] swizzled bf16
    const float* __restrict__ cache_k,  // [2][B][H][Q][64] fp32
    const float* __restrict__ cache_v,
    u16* __restrict__ AOb)              // [M_][2048] bf16
{
  __shared__ u16 Qs[128*64];
  __shared__ u16 Ps[128*64];
  __shared__ u16 Ks[2*64*64];
  __shared__ u16 Vt[2*64*64];

  const int bid = blockIdx.x;
  const int xcd = bid & 7, within = bid >> 3;
  const int w8 = within & 7;
  const int qtb = (w8 & 1) ? (7 - (w8 >> 1)) : (w8 >> 1);
  const int pair = xcd * 8 + (within >> 3);
  const int h = pair >> 1, b = pair & 1;
  const int bh = b * H_ + h;

  const int t = threadIdx.x;
  const int wave = t >> 6, lane = t & 63;
  const int g = lane >> 4, sub = lane & 15;
  const int wq0 = wave * 16;
  const int srow = lane >> 3;
  const int scc  = lane & 7;

  const u16* KbT = Kb + (size_t)bh * Q_ * 64;
  const u16* VtT = Vtb + (size_t)bh * 64 * Q_;

#define ATTN_STAGE(BUF, KT) do { \
    int r_ = wave*8 + srow; \
    GLOAD(KbT + (size_t)(((KT)<<6) + r_)*64 + scc*8, Ks + (BUF)*4096 + wave*512); \
    GLOAD(VtT + (size_t)r_*Q_ + ((KT)<<6) + scc*8,   Vt + (BUF)*4096 + wave*512); \
  } while(0)

  {
#pragma unroll
    for (int p = 0; p < 2; ++p) {
      int r = p*64 + wave*8 + srow;
      GLOAD(Yb + (size_t)(b*Q_ + qtb*128 + r)*QKVN_ + h*64 + ((scc ^ (r&7))<<3),
            Qs + p*4096 + wave*512);
    }
  }
  ATTN_STAGE(0, 0);
  asm volatile("s_waitcnt vmcnt(2)" ::: "memory");
  asm volatile("s_barrier" ::: "memory");

  bf16x8 qb[2];
#pragma unroll
  for (int kk = 0; kk < 2; ++kk) {
    int row = wq0 + sub;
    qb[kk] = *(const bf16x8*)&Qs[row*64 + (((4*kk+g) ^ (row&7))<<3)];
  }

  float m_run = -3e38f, l_run = 0.f;
  f32x4 acc_o[4] = {};
  int cur = 0;
  const int nkt = 2*qtb + 2;

  for (int kt = 0; kt < nkt; ++kt) {
    if (kt + 1 < nkt) {
      ATTN_STAGE(cur ^ 1, kt + 1);
      asm volatile("s_waitcnt vmcnt(2)" ::: "memory");
    } else {
      asm volatile("s_waitcnt vmcnt(0)" ::: "memory");
    }
    asm volatile("s_barrier" ::: "memory");

    if (kt*64 <= qtb*128 + wq0 + 15) {
      const u16* ksb = Ks + cur*4096;
      const u16* vtb = Vt + cur*4096;

      f32x4 s[4] = {};
      __builtin_amdgcn_s_setprio(1);
#pragma unroll
      for (int kk = 0; kk < 2; ++kk) {
        int kb = 4*kk + g;
#pragma unroll
        for (int cb = 0; cb < 4; ++cb) {
          int krow = cb*16 + sub;
          bf16x8 kf = *(const bf16x8*)&ksb[krow*64 + ((kb ^ (krow&7))<<3)];
          s[cb] = __builtin_amdgcn_mfma_f32_16x16x32_bf16(kf, qb[kk], s[cb], 0, 0, 0);
        }
      }
      __builtin_amdgcn_s_setprio(0);

      if (kt >= 2*qtb) {
#pragma unroll
        for (int cb = 0; cb < 4; ++cb)
#pragma unroll
          for (int r = 0; r < 4; ++r)
            if (kt*64 + cb*16 + 4*g + r > qtb*128 + wq0 + sub) s[cb][r] = -3e38f;
      }

      float mt = -3e38f;
#pragma unroll
      for (int cb = 0; cb < 4; ++cb)
#pragma unroll
        for (int r = 0; r < 4; ++r) mt = fmaxf(mt, s[cb][r]);
      mt = fmaxf(mt, __shfl_xor(mt, 16, 64));
      mt = fmaxf(mt, __shfl_xor(mt, 32, 64));

      float al = 1.0f;
      if (__any(mt > m_run + 8.f)) {
        float mnew = fmaxf(m_run, mt);
        al = __expf(m_run - mnew);
        m_run = mnew;
        int base = (lane & 48) + ((lane & 48) >> 2);
#pragma unroll
        for (int r = 0; r < 4; ++r) {
          float alr = __shfl(al, base + r, 64);
#pragma unroll
          for (int db = 0; db < 4; ++db) acc_o[db][r] *= alr;
        }
      }

      float sum = 0.f;
#pragma unroll
      for (int cb = 0; cb < 4; ++cb) {
        float p0 = __expf(s[cb][0]-m_run), p1 = __expf(s[cb][1]-m_run);
        float p2 = __expf(s[cb][2]-m_run), p3 = __expf(s[cb][3]-m_run);
        sum += (p0+p1)+(p2+p3);
        unsigned long long pk =
            (unsigned long long)((unsigned int)f2b(p0) | ((unsigned int)f2b(p1)<<16)) |
            ((unsigned long long)((unsigned int)f2b(p2) | ((unsigned int)f2b(p3)<<16)) << 32);
        int col8 = cb*2 + (g>>1);
        int dst = (wq0 + sub)*64 + ((col8 ^ (sub&7))<<3) + ((g&1)<<2);
        *(unsigned long long*)&Ps[dst] = pk;
      }
      sum += __shfl_xor(sum, 16, 64);
      sum += __shfl_xor(sum, 32, 64);
      l_run = l_run*al + sum;

      __builtin_amdgcn_s_setprio(1);
#pragma unroll
      for (int kk = 0; kk < 2; ++kk) {
        bf16x8 pa = *(const bf16x8*)&Ps[(wq0 + sub)*64 + (((4*kk+g) ^ (sub&7))<<3)];
#pragma unroll
        for (int db = 0; db < 4; ++db) {
          int drow = db*16 + sub;
          bf16x8 vf = *(const bf16x8*)&vtb[drow*64 + (((4*kk+g) ^ (drow&7))<<3)];
          acc_o[db] = __builtin_amdgcn_mfma_f32_16x16x32_bf16(pa, vf, acc_o[db], 0, 0, 0);
        }
      }
      __builtin_amdgcn_s_setprio(0);
    }
    asm volatile("s_barrier" ::: "memory");
    cur ^= 1;
  }
#undef ATTN_STAGE

  const int qrow_mine = wq0 + sub;
  const int qpos_mine = qtb*128 + qrow_mine;
  float e1 = 0.f, e2 = 0.f;
  {
    const float* k1p = cache_k + ((size_t)((B_ + b)*H_ + h)*Q_ + qpos_mine)*HD_ + g*16;
    const u16*   kfp = Yb + (size_t)(b*Q_ + qpos_mine)*QKVN_ + H_*HD_ + (h/NREP_)*HD_ + g*16;
    float qv[16];
#pragma unroll
    for (int half = 0; half < 2; ++half) {
      int kb = 2*g + half;
      bf16x8 qq = *(const bf16x8*)&Qs[qrow_mine*64 + ((kb ^ (qrow_mine&7))<<3)];
#pragma unroll
      for (int i = 0; i < 8; ++i) qv[half*8 + i] = b2f(((u16)qq[i]));
    }
    float4 kf4a = *(const float4*)kfp;
    float4 kf4b = *(const float4*)(kfp + 8);
    const u16* kf16a = (const u16*)&kf4a;
    const u16* kf16b = (const u16*)&kf4b;
#pragma unroll
    for (int c = 0; c < 4; ++c) {
      float4 kv1 = *(const float4*)(k1p + 4*c);
      e1 += qv[4*c]*kv1.x + qv[4*c+1]*kv1.y + qv[4*c+2]*kv1.z + qv[4*c+3]*kv1.w;
    }
#pragma unroll
    for (int i = 0; i < 8; ++i) {
      e2 += qv[i]   * b2f(kf16a[i]);
      e2 += qv[8+i] * b2f(kf16b[i]);
    }
  }
  e1 += __shfl_xor(e1, 16, 64); e1 += __shfl_xor(e1, 32, 64);
  e2 += __shfl_xor(e2, 16, 64); e2 += __shfl_xor(e2, 32, 64);

#pragma unroll
  for (int r = 0; r < 4; ++r) {
    int row = 4*g + r;
    int src = (lane & 48) | row;
    float e1r = __shfl(e1, src, 64);
    float e2r = __shfl(e2, src, 64);
    float m_r = __shfl(m_run, src, 64);
    float l_r = __shfl(l_run, src, 64);
    float mnew = fmaxf(m_r, fmaxf(e1r, e2r));
    float alr = __expf(m_r - mnew);
    float w1  = __expf(e1r - mnew);
    float w2  = __expf(e2r - mnew);
    float linv = 1.f / (l_r*alr + w1 + w2);
    int qpos = qtb*128 + wq0 + row;
    const float* v1p = cache_v + ((size_t)((B_ + b)*H_ + h)*Q_ + qpos)*HD_;
    const u16*   vfp = Yb + (size_t)(b*Q_ + qpos)*QKVN_ + (H_*HD_ + KVH_*HD_) + (h/NREP_)*HD_;
    u16* op = AOb + (size_t)(b*Q_ + qpos)*AOW_ + h*HD_;
#pragma unroll
    for (int db = 0; db < 4; ++db) {
      int d = db*16 + sub;
      float o = (acc_o[db][r]*alr + w1*v1p[d] + w2*b2f(vfp[d])) * linv;
      op[d] = f2b(o);
    }
  }
}

extern "C" void kernel_launch(void* const* d_in, const int* in_sizes, int n_in,
                              void* d_out, int out_size, void* d_ws, size_t ws_size,
                              hipStream_t stream) {
  const float* hidden  = (const float*)d_in[0];
  const float* Wq      = (const float*)d_in[1];
  const float* Wk      = (const float*)d_in[2];
  const float* Wv      = (const float*)d_in[3];
  const float* Wo      = (const float*)d_in[4];   // [HS][H*HD]
  const float* cache_k = (const float*)d_in[5];
  const float* cache_v = (const float*)d_in[6];
  const int*   pos_ids = (const int*)d_in[8];
  float* out = (float*)d_out;

  char* ws = (char*)d_ws;
  u16* Yb  = (u16*)ws;  ws += (size_t)M_ * QKVN_ * 2;
  u16* Xb  = (u16*)ws;  ws += (size_t)M_ * KIN_ * 2;
  u16* Wb  = (u16*)ws;  ws += (size_t)QKVN_ * KIN_ * 2;
  u16* Wob = (u16*)ws;  ws += (size_t)HS_ * AOW_ * 2;
  u16* Kb  = (u16*)ws;  ws += (size_t)B_*H_*Q_*64 * 2;
  u16* Vtb = (u16*)ws;  ws += (size_t)B_*H_*Q_*64 * 2;
  u16* AOb = Xb;                                           // Xb dead after QKV GEMM

  prep_kernel<<<dim3(3072), 256, 0, stream>>>(
      hidden, Wq, Wk, Wv, Wo, cache_k, cache_v, Xb, Wb, Wob, Kb, Vtb);

  // QKV GEMM with fused in-thread RoPE epilogue: grid 48x16 = 768 blocks
  gemm_nt<true><<<dim3(QKVN_/64, M_/128), 256, 0, stream>>>(Xb, Wb, (void*)Yb, KIN_, QKVN_, pos_ids);
  // attention: 512 blocks x 512 threads
  attn_mfma<<<dim3(512), 512, 0, stream>>>(Yb, Kb, Vtb, cache_k, cache_v, AOb);
  // Wo GEMM: grid 32x16 = 512 blocks, fp32 out
  gemm_nt<false><<<dim3(HS_/64, M_/128), 256, 0, stream>>>(AOb, Wob, (void*)out, AOW_, HS_, nullptr);
}